// Round 14
// baseline (96.554 us; speedup 1.0000x reference)
//
#include <hip/hip_runtime.h>

typedef unsigned short u16;
typedef short bf8 __attribute__((ext_vector_type(8)));
typedef float f4 __attribute__((ext_vector_type(4)));
typedef unsigned short us4 __attribute__((ext_vector_type(4)));

#define DEV static __device__ __forceinline__

DEV u16 f2bf(float x) {
  union { float f; unsigned u; } v; v.f = x;
  unsigned r = v.u + 0x7fffu + ((v.u >> 16) & 1u);  // RNE
  return (u16)(r >> 16);
}
DEV float bf2f(u16 h) {
  union { unsigned u; float f; } v; v.u = ((unsigned)h) << 16;
  return v.f;
}

constexpr int  NSP = 3136;                   // 56*56
constexpr long SZ1 = 2l * 256 * NSP;         // one (b,c,n) tensor, elems
constexpr float SCQ = 0.2550205145980166f;   // log2(e)/sqrt(32), folded into Q
// ws layout (u16 element offsets). ALL tensors fragment-major:
// unit = one 16(row)x32(k) MFMA operand tile = [64 lanes][8 elems] = 512 u16.
constexpr long OFF_XB  = 0;                  // per mod: [b][196 nblk][8 kblk][512]
constexpr long OFF_QB  = 2 * SZ1;            // per m:  [bh][196 u][512]
constexpr long OFF_KB  = 4 * SZ1;            // per m:  [bh][98 t][2 half][512] (sigma-permuted rows)
constexpr long OFF_VB  = 6 * SZ1;            // per mod:[bh][98 t][2 halfc][512]
constexpr long OFF_ATT = 8 * SZ1;            // [b][196 nblk][16 kblk][512]
constexpr long OFF_H   = 10 * SZ1;           // [b][196 nblk][8 kblk][512]
constexpr long OFF_WC  = 11 * SZ1;           // per mod: [48 mblk][8 kblk][512]
constexpr long OFF_WF1 = OFF_WC + 2l * 768 * 256;   // [16][16][512]
constexpr long OFF_WF2 = OFF_WF1 + 256l * 512;      // [16][8][512]
constexpr long END_BF16 = OFF_WF2 + 256l * 256;

// ---------------- fused: input conversion (blocks 0..195) + weight prep (rest) ----------------
__global__ __launch_bounds__(256) void k_cvtprep(
    const float* __restrict__ rgb, const float* __restrict__ dep,
    const float* __restrict__ wq_rd, const float* __restrict__ wk_r, const float* __restrict__ wv_r,
    const float* __restrict__ wq_dr, const float* __restrict__ wk_d, const float* __restrict__ wv_d,
    const float* __restrict__ wf1, const float* __restrict__ wf2,
    const float* __restrict__ bq_rd, const float* __restrict__ bk_r, const float* __restrict__ bv_r,
    const float* __restrict__ bq_dr, const float* __restrict__ bk_d, const float* __restrict__ bv_d,
    u16* __restrict__ wsb, float* __restrict__ wsf) {
  __shared__ u16 xs[256][68];
  const int blk = blockIdx.x;
  const int tid = threadIdx.x;
  if (blk < 196) {
    // ---- cvt path: f32 (b,c,n) -> bf16 fragment-major ----
    const int z = blk / 49, nt = blk - z * 49;   // z: 0,1 rgb b0/b1 ; 2,3 dep b0/b1
    const int mod = z >> 1, b = z & 1;
    const float* s = (mod ? dep : rgb) + (long)b * 256 * NSP;
    const int n0 = nt * 64;
#pragma unroll
    for (int p = 0; p < 8; ++p) {
      const int c = p * 32 + (tid >> 3);
      const int nl = (tid & 7) * 8;
      f4 v0 = *(const f4*)(s + (long)c * NSP + n0 + nl);
      f4 v1 = *(const f4*)(s + (long)c * NSP + n0 + nl + 4);
      us4 o0, o1;
      o0.x = f2bf(v0.x); o0.y = f2bf(v0.y); o0.z = f2bf(v0.z); o0.w = f2bf(v0.w);
      o1.x = f2bf(v1.x); o1.y = f2bf(v1.y); o1.z = f2bf(v1.z); o1.w = f2bf(v1.w);
      *(us4*)(&xs[c][nl]) = o0;
      *(us4*)(&xs[c][nl + 4]) = o1;
    }
    __syncthreads();
    const int lane = tid & 63, ul = tid >> 6;
    const int r = lane & 15, g = lane >> 4;
    u16* dst = wsb + OFF_XB + (long)mod * SZ1 + (long)b * 802816
             + (((long)((n0 >> 4) + ul)) * 8) * 512 + lane * 8;
    const int nn = ul * 16 + r;
#pragma unroll
    for (int kblk = 0; kblk < 8; ++kblk) {
      const int c0 = kblk * 32 + g * 8;
      us4 lo, hi;
      lo.x = xs[c0 + 0][nn]; lo.y = xs[c0 + 1][nn]; lo.z = xs[c0 + 2][nn]; lo.w = xs[c0 + 3][nn];
      hi.x = xs[c0 + 4][nn]; hi.y = xs[c0 + 5][nn]; hi.z = xs[c0 + 6][nn]; hi.w = xs[c0 + 7][nn];
      *(us4*)(dst + kblk * 512) = lo;
      *(us4*)(dst + kblk * 512 + 4) = hi;
    }
    return;
  }
  // ---- prep path: concat weights + bf16, fragment-major; zero wsf accumulators ----
  long idx = (long)(blk - 196) * 256 + tid;
  const long WCN = 2l * 768 * 256;  // 393216
  if (idx < WCN) {
    int mod = idx >= 768l * 256;
    long f = idx - (mod ? 768l * 256 : 0);
    int j = (int)f & 7, ln = ((int)f >> 3) & 63, unit = (int)(f >> 9);
    int kblk = unit & 7, mblk = unit >> 3;
    int row = mblk * 16 + (ln & 15), col = kblk * 32 + (ln >> 4) * 8 + j;
    int seg = row >> 8, r2 = row & 255;
    const float* src;
    if (!mod) src = seg == 0 ? wq_rd : (seg == 1 ? wk_r : wv_r);
    else      src = seg == 0 ? wq_dr : (seg == 1 ? wk_d : wv_d);
    wsb[OFF_WC + idx] = f2bf(src[r2 * 256 + col]);
    return;
  }
  long jx = idx - WCN;
  if (jx < 256l * 512) {
    int j = (int)jx & 7, ln = ((int)jx >> 3) & 63, unit = (int)(jx >> 9);
    int kblk = unit & 15, mblk = unit >> 4;
    int row = mblk * 16 + (ln & 15), col = kblk * 32 + (ln >> 4) * 8 + j;
    wsb[OFF_WF1 + jx] = f2bf(wf1[row * 512 + col]);
    return;
  }
  jx -= 256l * 512;
  if (jx < 256l * 256) {
    int j = (int)jx & 7, ln = ((int)jx >> 3) & 63, unit = (int)(jx >> 9);
    int kblk = unit & 7, mblk = unit >> 3;
    int row = mblk * 16 + (ln & 15), col = kblk * 32 + (ln >> 4) * 8 + j;
    wsb[OFF_WF2 + jx] = f2bf(wf2[row * 256 + col]);
    return;
  }
  jx -= 256l * 256;
  if (jx < 1536) {
    int mod = jx >= 768;
    int row = (int)jx - (mod ? 768 : 0);
    int seg = row >> 8, r2 = row & 255;
    const float* src;
    if (!mod) src = seg == 0 ? bq_rd : (seg == 1 ? bk_r : bv_r);
    else      src = seg == 0 ? bq_dr : (seg == 1 ? bk_d : bv_d);
    wsf[1028 + jx] = src[r2];          // bcat
    return;
  }
  jx -= 1536;
  if (jx < 1028) wsf[jx] = 0.f;        // att2(4) + qsums(512) + ksums(512)
}

// ---------------- GEMM (fragment-major, LDS-free; 128x64 block tile, 4x2 acc/wave) ----------------
// SPLIT=1: 4 waves (wm,wn).  SPLIT=2: 8 waves (wm,wn,ks) — 2-way K-split, LDS combine.
// EPI 0: QKV (z = b*2+mod), M=768 -> QF (xSCQ) / KF (sigma) / VF fragment layouts
// EPI 1: fusion1 (z = b), K=512, bias+BN+ReLU -> H fragment layout; z==2: amap finish
// EPI 2: fusion2 (z = b), K=256, bias -> f32 d_out (b,c,n)
template <int KDIM, int EPI, int SPLIT>
__global__ __launch_bounds__(SPLIT * 256) void k_gemm(
    u16* __restrict__ wsb, const float* __restrict__ bcat,
    const float* __restrict__ bf1, const float* __restrict__ gamma,
    const float* __restrict__ beta, const float* __restrict__ bf2,
    const float* __restrict__ qsums, const float* __restrict__ ksums,
    float* __restrict__ outf) {
  constexpr int KB = KDIM / 32;
  const int tid = threadIdx.x;

  if constexpr (EPI == 1) {
    if (blockIdx.z == 2) {             // fused amap finish + broadcast (all threads participate)
      if (blockIdx.y != 0 || blockIdx.x >= 2) return;
      const int b = blockIdx.x;
      __shared__ float sd[SPLIT * 256];
      float v = 0.f;
      if (tid < 256) v = qsums[b * 256 + tid] * ksums[b * 256 + tid];
      sd[tid] = v; __syncthreads();
#pragma unroll
      for (int off = SPLIT * 128; off; off >>= 1) {
        if (tid < off) sd[tid] += sd[tid + off];
        __syncthreads();
      }
      const float av = sd[0] * (1.0f / (8.0f * 3136.0f * 3136.0f * SCQ));
      float* dst = outf + 2l * 256 * NSP + (long)b * NSP;
      for (int i = tid; i < NSP; i += SPLIT * 256) dst[i] = av;
      return;
    }
  }

  const int lane = tid & 63, wid = tid >> 6;
  const int g = lane >> 4, r = lane & 15;
  int wm, wn, ks;
  if constexpr (SPLIT == 2) { ks = wid & 1; wn = (wid >> 1) & 1; wm = wid >> 2; }
  else                      { ks = 0; wn = wid & 1; wm = wid >> 1; }
  const int n0 = blockIdx.x * 64;
  const int m0 = blockIdx.y * 128;
  const int z = blockIdx.z;

  int b = 0, mod = 0;
  const u16* In; const u16* W;
  if constexpr (EPI == 0) {
    mod = z & 1; b = z >> 1;
    In = wsb + OFF_XB + (long)mod * SZ1 + (long)b * 802816;
    W  = wsb + OFF_WC + (long)mod * 768 * 256;
  } else if constexpr (EPI == 1) {
    b = z;
    In = wsb + OFF_ATT + (long)b * NSP * 512;
    W  = wsb + OFF_WF1;
  } else {
    b = z;
    In = wsb + OFF_H + (long)b * 802816;
    W  = wsb + OFF_WF2;
  }

  const int M0 = m0 + wm * 64;
  const u16* Abase = W + ((long)(M0 >> 4) * KB) * 512 + lane * 8;
  const u16* Bbase = In + ((long)((n0 >> 4) + wn * 2) * KB) * 512 + lane * 8;

  const f4 zero4 = {0.f, 0.f, 0.f, 0.f};
  f4 acc[4][2];
#pragma unroll
  for (int i = 0; i < 4; ++i)
#pragma unroll
    for (int j = 0; j < 2; ++j) acc[i][j] = zero4;

  const int kb0 = ks * (KB / SPLIT), kb1 = (ks + 1) * (KB / SPLIT);
#pragma unroll 8
  for (int kb = kb0; kb < kb1; ++kb) {
    bf8 aw[4], bx[2];
#pragma unroll
    for (int i = 0; i < 4; ++i)
      aw[i] = *(const bf8*)(Abase + ((long)i * KB + kb) * 512);
#pragma unroll
    for (int jn = 0; jn < 2; ++jn)
      bx[jn] = *(const bf8*)(Bbase + ((long)jn * KB + kb) * 512);
#pragma unroll
    for (int i = 0; i < 4; ++i)
#pragma unroll
      for (int jn = 0; jn < 2; ++jn)
        acc[i][jn] = __builtin_amdgcn_mfma_f32_16x16x32_bf16(aw[i], bx[jn], acc[i][jn], 0, 0, 0);
  }

  if constexpr (SPLIT == 2) {
    __shared__ f4 sc[2][2][8][64];
    if (ks) {
#pragma unroll
      for (int i = 0; i < 4; ++i)
#pragma unroll
        for (int j = 0; j < 2; ++j) sc[wm][wn][i * 2 + j][lane] = acc[i][j];
    }
    __syncthreads();
    if (ks) return;
#pragma unroll
    for (int i = 0; i < 4; ++i)
#pragma unroll
      for (int j = 0; j < 2; ++j) acc[i][j] += sc[wm][wn][i * 2 + j][lane];
  }

  const int seg = M0 >> 8;  // uniform per wave
#pragma unroll
  for (int i = 0; i < 4; ++i) {
    const int orow = M0 + i * 16 + 4 * g;  // + reg q
#pragma unroll
    for (int jn = 0; jn < 2; ++jn) {
      const int n = n0 + wn * 32 + jn * 16 + r;
      f4 a = acc[i][jn];
      if constexpr (EPI == 0) {
        const int ol = orow & 255;
        const float* bs = bcat + mod * 768 + seg * 256 + ol;
        const float qs = (seg == 0) ? SCQ : 1.0f;
        float a0 = (a.x + bs[0]) * qs, a1 = (a.y + bs[1]) * qs;
        float a2 = (a.z + bs[2]) * qs, a3 = (a.w + bs[3]) * qs;
        if (seg == 0) {
          const int hh = ol >> 5, hd0 = ol & 31;
          us4 pk; pk.x = f2bf(a0); pk.y = f2bf(a1); pk.z = f2bf(a2); pk.w = f2bf(a3);
          *(us4*)(wsb + OFF_QB + mod * SZ1
                  + (((long)(b * 8 + hh) * 196 + (n >> 4)) << 9)
                  + ((hd0 >> 3) * 16 + (n & 15)) * 8 + (hd0 & 7)) = pk;
        } else if (seg == 1) {
          const int hh = ol >> 5, hd0 = ol & 31;
          const int t = n >> 5, rr = n & 31;
          const int half = (rr >> 2) & 1, rK = ((rr >> 3) << 2) | (rr & 3);
          us4 pk; pk.x = f2bf(a0); pk.y = f2bf(a1); pk.z = f2bf(a2); pk.w = f2bf(a3);
          *(us4*)(wsb + OFF_KB + mod * SZ1
                  + ((((long)(b * 8 + hh) * 98 + t) * 2 + half) << 9)
                  + ((hd0 >> 3) * 16 + rK) * 8 + (hd0 & 7)) = pk;
        } else {
          const int hh = ol >> 5, rem = ol & 31, halfc = rem >> 4, rv = rem & 15;
          const int t = n >> 5, gp = (n >> 3) & 3, jj = n & 7;
          u16* dst = wsb + OFF_VB + mod * SZ1
                   + ((((long)(b * 8 + hh) * 98 + t) * 2 + halfc) << 9)
                   + (gp * 16 + rv) * 8 + jj;
          dst[0] = f2bf(a0); dst[8] = f2bf(a1); dst[16] = f2bf(a2); dst[24] = f2bf(a3);
        }
      } else if constexpr (EPI == 1) {
        us4 pk;
#pragma unroll
        for (int q = 0; q < 4; ++q) {
          const int o = orow + q;
          float v = (a[q] + bf1[o]) * (gamma[o] * 0.9999950000374994f) + beta[o];
          pk[q] = f2bf(fmaxf(v, 0.f));
        }
        const int ch0 = orow;
        *(us4*)(wsb + OFF_H + ((((long)b * 196 + (n >> 4)) * 8 + (ch0 >> 5)) << 9)
                + (((ch0 >> 3) & 3) * 16 + (n & 15)) * 8 + (ch0 & 7)) = pk;
      } else {
#pragma unroll
        for (int q = 0; q < 4; ++q) {
          const int o = orow + q;
          outf[(long)(b * 256 + o) * NSP + n] = a[q] + bf2[o];
        }
      }
    }
  }
}

// ---------------- flash attention (no-max softmax; fragment-major Q/K/V) ----------------
// 8 waves/block = (qhalf x 4-way kv-split); 32 q-rows/wave; additive LDS combine.
// T5: s_setprio(1) around MFMA bursts so MFMA-entering waves win issue arbitration
// over VALU(exp2)-phase waves. z==2 slice: attention-map partial reduction.
DEV bf8 pack_p(f4 s0, f4 s1) {
  union { unsigned u[4]; bf8 v; } p;
  float a0 = __builtin_amdgcn_exp2f(s0.x), a1 = __builtin_amdgcn_exp2f(s0.y);
  float a2 = __builtin_amdgcn_exp2f(s0.z), a3 = __builtin_amdgcn_exp2f(s0.w);
  float a4 = __builtin_amdgcn_exp2f(s1.x), a5 = __builtin_amdgcn_exp2f(s1.y);
  float a6 = __builtin_amdgcn_exp2f(s1.z), a7 = __builtin_amdgcn_exp2f(s1.w);
  asm("v_cvt_pk_bf16_f32 %0, %1, %2" : "=v"(p.u[0]) : "v"(a0), "v"(a1));
  asm("v_cvt_pk_bf16_f32 %0, %1, %2" : "=v"(p.u[1]) : "v"(a2), "v"(a3));
  asm("v_cvt_pk_bf16_f32 %0, %1, %2" : "=v"(p.u[2]) : "v"(a4), "v"(a5));
  asm("v_cvt_pk_bf16_f32 %0, %1, %2" : "=v"(p.u[3]) : "v"(a6), "v"(a7));
  return p.v;
}

__global__ __launch_bounds__(512) void k_attn(u16* __restrict__ wsb,
                                              float* __restrict__ qsums,
                                              float* __restrict__ ksums) {
  const int tid = threadIdx.x;
  if (blockIdx.z == 2) {
    // ---- amap partial reduction: per-(bh, d) column sums of Q_rgb, K_depth ----
    if (blockIdx.x >= 7 || tid >= 256) return;
    const int split = blockIdx.x;
    const int bh = blockIdx.y;
    const int d = tid & 31, ns = tid >> 5;
    const u16* qb = wsb + OFF_QB + ((long)bh * 196) * 512 + ((d >> 3) * 16) * 8 + (d & 7);
    const u16* kb = wsb + OFF_KB + SZ1 + ((long)bh * 196) * 512 + ((d >> 3) * 16) * 8 + (d & 7);
    float qs = 0.f, ks = 0.f;
    for (int u = split * 28 + ns; u < split * 28 + 28; u += 8) {
      const long ub = (long)u << 9;
#pragma unroll
      for (int rr = 0; rr < 16; ++rr) {
        qs += bf2f(qb[ub + rr * 8]);
        ks += bf2f(kb[ub + rr * 8]);
      }
    }
    __shared__ float sq[256], sk[256];
    sq[tid] = qs; sk[tid] = ks;
    __syncthreads();
    if (tid < 32) {
#pragma unroll
      for (int j = 1; j < 8; ++j) { qs += sq[tid + 32 * j]; ks += sk[tid + 32 * j]; }
      atomicAdd(qsums + bh * 32 + tid, qs);
      atomicAdd(ksums + bh * 32 + tid, ks);
    }
    return;
  }

  const int m = blockIdx.z;
  const int bh = blockIdx.y;
  const int b = bh >> 3, h = bh & 7;
  const int lane = tid & 63, wid = tid >> 6;
  const int qh = wid & 1, kvh = wid >> 1;    // qh 0..1, kvh 0..3
  const int g = lane >> 4, r = lane & 15;
  const int q0 = blockIdx.x * 64 + qh * 32;

  const u16* QF = wsb + OFF_QB + (long)m * SZ1 + ((long)bh * 196) * 512;
  const u16* KF = wsb + OFF_KB + (long)(1 - m) * SZ1 + ((long)bh * 196) * 512;
  const u16* VF = wsb + OFF_VB + (long)(1 - m) * SZ1 + ((long)bh * 196) * 512;

  const bf8 qfA = *(const bf8*)(QF + ((long)(q0 >> 4) << 9) + lane * 8);
  const bf8 qfB = *(const bf8*)(QF + ((long)((q0 >> 4) + 1) << 9) + lane * 8);
  // kv 64-row tiles: 49 total, split 13/12/12/12 across kvh
  const int tb = kvh ? (13 + 12 * (kvh - 1)) : 0;
  const int te = tb + (kvh ? 12 : 13);
  const u16* kp = KF + ((long)tb << 11) + lane * 8;
  const u16* vp = VF + ((long)tb << 11) + lane * 8;

  bf8 ones;
#pragma unroll
  for (int j = 0; j < 8; ++j) ones[j] = (short)0x3F80;  // bf16 1.0

  const f4 zero4 = {0.f, 0.f, 0.f, 0.f};
  f4 oA0 = zero4, oA1 = zero4, oB0 = zero4, oB1 = zero4;
  f4 lA = zero4, lB = zero4;

  for (int t = tb; t < te; ++t) {
    const bf8 kf0 = *(const bf8*)(kp);
    const bf8 kf1 = *(const bf8*)(kp + 512);
    const bf8 kf2 = *(const bf8*)(kp + 1024);
    const bf8 kf3 = *(const bf8*)(kp + 1536);
    kp += 2048;
    const bf8 v0a = *(const bf8*)(vp);
    const bf8 v1a = *(const bf8*)(vp + 512);
    const bf8 v0b = *(const bf8*)(vp + 1024);
    const bf8 v1b = *(const bf8*)(vp + 1536);
    vp += 2048;

    // group A (q = q0 + r)
    {
      __builtin_amdgcn_s_setprio(1);
      f4 s0 = __builtin_amdgcn_mfma_f32_16x16x32_bf16(kf0, qfA, zero4, 0, 0, 0);
      f4 s1 = __builtin_amdgcn_mfma_f32_16x16x32_bf16(kf1, qfA, zero4, 0, 0, 0);
      f4 s2 = __builtin_amdgcn_mfma_f32_16x16x32_bf16(kf2, qfA, zero4, 0, 0, 0);
      f4 s3 = __builtin_amdgcn_mfma_f32_16x16x32_bf16(kf3, qfA, zero4, 0, 0, 0);
      __builtin_amdgcn_s_setprio(0);
      bf8 p0 = pack_p(s0, s1);   // kv .. kv+31
      bf8 p1 = pack_p(s2, s3);   // kv+32 .. kv+63
      __builtin_amdgcn_s_setprio(1);
      lA  = __builtin_amdgcn_mfma_f32_16x16x32_bf16(ones, p0, lA, 0, 0, 0);
      lA  = __builtin_amdgcn_mfma_f32_16x16x32_bf16(ones, p1, lA, 0, 0, 0);
      oA0 = __builtin_amdgcn_mfma_f32_16x16x32_bf16(v0a, p0, oA0, 0, 0, 0);
      oA0 = __builtin_amdgcn_mfma_f32_16x16x32_bf16(v0b, p1, oA0, 0, 0, 0);
      oA1 = __builtin_amdgcn_mfma_f32_16x16x32_bf16(v1a, p0, oA1, 0, 0, 0);
      oA1 = __builtin_amdgcn_mfma_f32_16x16x32_bf16(v1b, p1, oA1, 0, 0, 0);
      __builtin_amdgcn_s_setprio(0);
    }
    // group B (q = q0 + 16 + r)
    {
      __builtin_amdgcn_s_setprio(1);
      f4 s0 = __builtin_amdgcn_mfma_f32_16x16x32_bf16(kf0, qfB, zero4, 0, 0, 0);
      f4 s1 = __builtin_amdgcn_mfma_f32_16x16x32_bf16(kf1, qfB, zero4, 0, 0, 0);
      f4 s2 = __builtin_amdgcn_mfma_f32_16x16x32_bf16(kf2, qfB, zero4, 0, 0, 0);
      f4 s3 = __builtin_amdgcn_mfma_f32_16x16x32_bf16(kf3, qfB, zero4, 0, 0, 0);
      __builtin_amdgcn_s_setprio(0);
      bf8 p0 = pack_p(s0, s1);
      bf8 p1 = pack_p(s2, s3);
      __builtin_amdgcn_s_setprio(1);
      lB  = __builtin_amdgcn_mfma_f32_16x16x32_bf16(ones, p0, lB, 0, 0, 0);
      lB  = __builtin_amdgcn_mfma_f32_16x16x32_bf16(ones, p1, lB, 0, 0, 0);
      oB0 = __builtin_amdgcn_mfma_f32_16x16x32_bf16(v0a, p0, oB0, 0, 0, 0);
      oB0 = __builtin_amdgcn_mfma_f32_16x16x32_bf16(v0b, p1, oB0, 0, 0, 0);
      oB1 = __builtin_amdgcn_mfma_f32_16x16x32_bf16(v1a, p0, oB1, 0, 0, 0);
      oB1 = __builtin_amdgcn_mfma_f32_16x16x32_bf16(v1b, p1, oB1, 0, 0, 0);
      __builtin_amdgcn_s_setprio(0);
    }
  }

  // combine 4 kv-partials per q-half (additive: no-max softmax) via LDS
  __shared__ f4 so[2][3][4][64];
  __shared__ float sl[2][3][2][64];
  if (kvh) {
    so[qh][kvh - 1][0][lane] = oA0; so[qh][kvh - 1][1][lane] = oA1;
    so[qh][kvh - 1][2][lane] = oB0; so[qh][kvh - 1][3][lane] = oB1;
    sl[qh][kvh - 1][0][lane] = lA.x; sl[qh][kvh - 1][1][lane] = lB.x;
  }
  __syncthreads();
  if (!kvh) {
#pragma unroll
    for (int w = 0; w < 3; ++w) {
      oA0 += so[qh][w][0][lane]; oA1 += so[qh][w][1][lane];
      oB0 += so[qh][w][2][lane]; oB1 += so[qh][w][3][lane];
      lA.x += sl[qh][w][0][lane]; lB.x += sl[qh][w][1][lane];
    }
    const float invA = 1.0f / lA.x;
    const float invB = 1.0f / lB.x;
    oA0 *= invA; oA1 *= invA; oB0 *= invB; oB1 *= invB;

    // ATT fragment layout: [b][196 u][16 kblk][512]; n = q0+r (A) / q0+16+r (B)
    u16* ab = wsb + OFF_ATT + ((((long)b * 196 + (q0 >> 4)) * 16) + m * 8 + h) * 512;
    const int ld0 = ((g >> 1) * 16 + r) * 8 + 4 * (g & 1);
    us4 w0, w1, w2, w3;
#pragma unroll
    for (int q = 0; q < 4; ++q) {
      w0[q] = f2bf(oA0[q]); w1[q] = f2bf(oA1[q]);
      w2[q] = f2bf(oB0[q]); w3[q] = f2bf(oB1[q]);
    }
    *(us4*)(ab + ld0) = w0;
    *(us4*)(ab + ld0 + 256) = w1;
    *(us4*)(ab + 8192 + ld0) = w2;
    *(us4*)(ab + 8192 + ld0 + 256) = w3;
  }
}

// ---------------- launch ----------------
extern "C" void kernel_launch(void* const* d_in, const int* in_sizes, int n_in,
                              void* d_out, int out_size, void* d_ws, size_t ws_size,
                              hipStream_t stream) {
  const float* rgb   = (const float*)d_in[0];
  const float* dep   = (const float*)d_in[1];
  const float* Wq_rd = (const float*)d_in[2];
  const float* bq_rd = (const float*)d_in[3];
  const float* Wk_d  = (const float*)d_in[4];
  const float* bk_d  = (const float*)d_in[5];
  const float* Wv_d  = (const float*)d_in[6];
  const float* bv_d  = (const float*)d_in[7];
  const float* Wq_dr = (const float*)d_in[8];
  const float* bq_dr = (const float*)d_in[9];
  const float* Wk_r  = (const float*)d_in[10];
  const float* bk_r  = (const float*)d_in[11];
  const float* Wv_r  = (const float*)d_in[12];
  const float* bv_r  = (const float*)d_in[13];
  const float* Wf1   = (const float*)d_in[14];
  const float* bf1   = (const float*)d_in[15];
  const float* gamma = (const float*)d_in[16];
  const float* beta  = (const float*)d_in[17];
  const float* Wf2   = (const float*)d_in[18];
  const float* bf2   = (const float*)d_in[19];
  float* out = (float*)d_out;

  u16* wsb = (u16*)d_ws;
  float* wsf = (float*)((char*)d_ws + (size_t)END_BF16 * 2);
  float* qsums = wsf + 4;        // 512
  float* ksums = wsf + 4 + 512;  // 512
  float* bcat  = wsf + 1028;     // 1536
  const size_t needed = (size_t)END_BF16 * 2 + (4 + 1024 + 1536) * sizeof(float);
  if (ws_size < needed) return;

  k_cvtprep<<<2511, 256, 0, stream>>>(rgb, dep,
                                      Wq_rd, Wk_r, Wv_r, Wq_dr, Wk_d, Wv_d, Wf1, Wf2,
                                      bq_rd, bk_r, bv_r, bq_dr, bk_d, bv_d, wsb, wsf);
  k_gemm<256, 0, 1><<<dim3(49, 6, 4), 256, 0, stream>>>(wsb, bcat, nullptr, nullptr, nullptr, nullptr, nullptr, nullptr, nullptr);
  k_attn<<<dim3(49, 16, 3), 512, 0, stream>>>(wsb, qsums, ksums);
  k_gemm<512, 1, 2><<<dim3(49, 2, 3), 512, 0, stream>>>(wsb, nullptr, bf1, gamma, beta, nullptr, qsums, ksums, out);
  k_gemm<256, 2, 2><<<dim3(49, 2, 2), 512, 0, stream>>>(wsb, nullptr, nullptr, nullptr, nullptr, bf2, nullptr, nullptr, out);
}

// Round 15
// 95.880 us; speedup vs baseline: 1.0070x; 1.0070x over previous
//
#include <hip/hip_runtime.h>

typedef unsigned short u16;
typedef short bf8 __attribute__((ext_vector_type(8)));
typedef float f4 __attribute__((ext_vector_type(4)));
typedef unsigned short us4 __attribute__((ext_vector_type(4)));

#define DEV static __device__ __forceinline__

DEV u16 f2bf(float x) {
  union { float f; unsigned u; } v; v.f = x;
  unsigned r = v.u + 0x7fffu + ((v.u >> 16) & 1u);  // RNE
  return (u16)(r >> 16);
}
DEV float bf2f(u16 h) {
  union { unsigned u; float f; } v; v.u = ((unsigned)h) << 16;
  return v.f;
}

constexpr int  NSP = 3136;                   // 56*56
constexpr long SZ1 = 2l * 256 * NSP;         // one (b,c,n) tensor, elems
constexpr float SCQ = 0.2550205145980166f;   // log2(e)/sqrt(32), folded into Q
// ws layout (u16 element offsets). ALL tensors fragment-major:
// unit = one 16(row)x32(k) MFMA operand tile = [64 lanes][8 elems] = 512 u16.
constexpr long OFF_XB  = 0;                  // per mod: [b][196 nblk][8 kblk][512]
constexpr long OFF_QB  = 2 * SZ1;            // per m:  [bh][196 u][512]
constexpr long OFF_KB  = 4 * SZ1;            // per m:  [bh][98 t][2 half][512] (sigma-permuted rows)
constexpr long OFF_VB  = 6 * SZ1;            // per mod:[bh][98 t][2 halfc][512]
constexpr long OFF_ATT = 8 * SZ1;            // [b][196 nblk][16 kblk][512]
constexpr long OFF_H   = 10 * SZ1;           // [b][196 nblk][8 kblk][512]
constexpr long OFF_WC  = 11 * SZ1;           // per mod: [48 mblk][8 kblk][512]
constexpr long OFF_WF1 = OFF_WC + 2l * 768 * 256;   // [16][16][512]
constexpr long OFF_WF2 = OFF_WF1 + 256l * 512;      // [16][8][512]
constexpr long END_BF16 = OFF_WF2 + 256l * 256;

// ---------------- fused: input conversion (blocks 0..195) + weight prep (rest) ----------------
__global__ __launch_bounds__(256) void k_cvtprep(
    const float* __restrict__ rgb, const float* __restrict__ dep,
    const float* __restrict__ wq_rd, const float* __restrict__ wk_r, const float* __restrict__ wv_r,
    const float* __restrict__ wq_dr, const float* __restrict__ wk_d, const float* __restrict__ wv_d,
    const float* __restrict__ wf1, const float* __restrict__ wf2,
    const float* __restrict__ bq_rd, const float* __restrict__ bk_r, const float* __restrict__ bv_r,
    const float* __restrict__ bq_dr, const float* __restrict__ bk_d, const float* __restrict__ bv_d,
    u16* __restrict__ wsb, float* __restrict__ wsf) {
  __shared__ u16 xs[256][68];
  const int blk = blockIdx.x;
  const int tid = threadIdx.x;
  if (blk < 196) {
    // ---- cvt path: f32 (b,c,n) -> bf16 fragment-major ----
    const int z = blk / 49, nt = blk - z * 49;   // z: 0,1 rgb b0/b1 ; 2,3 dep b0/b1
    const int mod = z >> 1, b = z & 1;
    const float* s = (mod ? dep : rgb) + (long)b * 256 * NSP;
    const int n0 = nt * 64;
#pragma unroll
    for (int p = 0; p < 8; ++p) {
      const int c = p * 32 + (tid >> 3);
      const int nl = (tid & 7) * 8;
      f4 v0 = *(const f4*)(s + (long)c * NSP + n0 + nl);
      f4 v1 = *(const f4*)(s + (long)c * NSP + n0 + nl + 4);
      us4 o0, o1;
      o0.x = f2bf(v0.x); o0.y = f2bf(v0.y); o0.z = f2bf(v0.z); o0.w = f2bf(v0.w);
      o1.x = f2bf(v1.x); o1.y = f2bf(v1.y); o1.z = f2bf(v1.z); o1.w = f2bf(v1.w);
      *(us4*)(&xs[c][nl]) = o0;
      *(us4*)(&xs[c][nl + 4]) = o1;
    }
    __syncthreads();
    const int lane = tid & 63, ul = tid >> 6;
    const int r = lane & 15, g = lane >> 4;
    u16* dst = wsb + OFF_XB + (long)mod * SZ1 + (long)b * 802816
             + (((long)((n0 >> 4) + ul)) * 8) * 512 + lane * 8;
    const int nn = ul * 16 + r;
#pragma unroll
    for (int kblk = 0; kblk < 8; ++kblk) {
      const int c0 = kblk * 32 + g * 8;
      us4 lo, hi;
      lo.x = xs[c0 + 0][nn]; lo.y = xs[c0 + 1][nn]; lo.z = xs[c0 + 2][nn]; lo.w = xs[c0 + 3][nn];
      hi.x = xs[c0 + 4][nn]; hi.y = xs[c0 + 5][nn]; hi.z = xs[c0 + 6][nn]; hi.w = xs[c0 + 7][nn];
      *(us4*)(dst + kblk * 512) = lo;
      *(us4*)(dst + kblk * 512 + 4) = hi;
    }
    return;
  }
  // ---- prep path: concat weights + bf16, fragment-major; zero wsf accumulators ----
  long idx = (long)(blk - 196) * 256 + tid;
  const long WCN = 2l * 768 * 256;  // 393216
  if (idx < WCN) {
    int mod = idx >= 768l * 256;
    long f = idx - (mod ? 768l * 256 : 0);
    int j = (int)f & 7, ln = ((int)f >> 3) & 63, unit = (int)(f >> 9);
    int kblk = unit & 7, mblk = unit >> 3;
    int row = mblk * 16 + (ln & 15), col = kblk * 32 + (ln >> 4) * 8 + j;
    int seg = row >> 8, r2 = row & 255;
    const float* src;
    if (!mod) src = seg == 0 ? wq_rd : (seg == 1 ? wk_r : wv_r);
    else      src = seg == 0 ? wq_dr : (seg == 1 ? wk_d : wv_d);
    wsb[OFF_WC + idx] = f2bf(src[r2 * 256 + col]);
    return;
  }
  long jx = idx - WCN;
  if (jx < 256l * 512) {
    int j = (int)jx & 7, ln = ((int)jx >> 3) & 63, unit = (int)(jx >> 9);
    int kblk = unit & 15, mblk = unit >> 4;
    int row = mblk * 16 + (ln & 15), col = kblk * 32 + (ln >> 4) * 8 + j;
    wsb[OFF_WF1 + jx] = f2bf(wf1[row * 512 + col]);
    return;
  }
  jx -= 256l * 512;
  if (jx < 256l * 256) {
    int j = (int)jx & 7, ln = ((int)jx >> 3) & 63, unit = (int)(jx >> 9);
    int kblk = unit & 7, mblk = unit >> 3;
    int row = mblk * 16 + (ln & 15), col = kblk * 32 + (ln >> 4) * 8 + j;
    wsb[OFF_WF2 + jx] = f2bf(wf2[row * 256 + col]);
    return;
  }
  jx -= 256l * 256;
  if (jx < 1536) {
    int mod = jx >= 768;
    int row = (int)jx - (mod ? 768 : 0);
    int seg = row >> 8, r2 = row & 255;
    const float* src;
    if (!mod) src = seg == 0 ? bq_rd : (seg == 1 ? bk_r : bv_r);
    else      src = seg == 0 ? bq_dr : (seg == 1 ? bk_d : bv_d);
    wsf[1028 + jx] = src[r2];          // bcat
    return;
  }
  jx -= 1536;
  if (jx < 1028) wsf[jx] = 0.f;        // att2(4) + qsums(512) + ksums(512)
}

// ---------------- GEMM (fragment-major, LDS-free; 128x64 block tile, 4x2 acc/wave) ----------------
// SPLIT=1: 4 waves (wm,wn).  SPLIT=2: 8 waves (wm,wn,ks) — 2-way K-split, LDS combine.
// EPI 0: QKV (z = b*2+mod), M=768 -> QF (xSCQ) / KF (sigma) / VF fragment layouts
// EPI 1: fusion1 (z = b), K=512, bias+BN+ReLU -> H fragment layout; z==2: amap finish
// EPI 2: fusion2 (z = b), K=256, bias -> f32 d_out (b,c,n)
template <int KDIM, int EPI, int SPLIT>
__global__ __launch_bounds__(SPLIT * 256) void k_gemm(
    u16* __restrict__ wsb, const float* __restrict__ bcat,
    const float* __restrict__ bf1, const float* __restrict__ gamma,
    const float* __restrict__ beta, const float* __restrict__ bf2,
    const float* __restrict__ qsums, const float* __restrict__ ksums,
    float* __restrict__ outf) {
  constexpr int KB = KDIM / 32;
  const int tid = threadIdx.x;

  if constexpr (EPI == 1) {
    if (blockIdx.z == 2) {             // fused amap finish + broadcast (all threads participate)
      if (blockIdx.y != 0 || blockIdx.x >= 2) return;
      const int b = blockIdx.x;
      __shared__ float sd[SPLIT * 256];
      float v = 0.f;
      if (tid < 256) v = qsums[b * 256 + tid] * ksums[b * 256 + tid];
      sd[tid] = v; __syncthreads();
#pragma unroll
      for (int off = SPLIT * 128; off; off >>= 1) {
        if (tid < off) sd[tid] += sd[tid + off];
        __syncthreads();
      }
      const float av = sd[0] * (1.0f / (8.0f * 3136.0f * 3136.0f * SCQ));
      float* dst = outf + 2l * 256 * NSP + (long)b * NSP;
      for (int i = tid; i < NSP; i += SPLIT * 256) dst[i] = av;
      return;
    }
  }

  const int lane = tid & 63, wid = tid >> 6;
  const int g = lane >> 4, r = lane & 15;
  int wm, wn, ks;
  if constexpr (SPLIT == 2) { ks = wid & 1; wn = (wid >> 1) & 1; wm = wid >> 2; }
  else                      { ks = 0; wn = wid & 1; wm = wid >> 1; }
  const int n0 = blockIdx.x * 64;
  const int m0 = blockIdx.y * 128;
  const int z = blockIdx.z;

  int b = 0, mod = 0;
  const u16* In; const u16* W;
  if constexpr (EPI == 0) {
    mod = z & 1; b = z >> 1;
    In = wsb + OFF_XB + (long)mod * SZ1 + (long)b * 802816;
    W  = wsb + OFF_WC + (long)mod * 768 * 256;
  } else if constexpr (EPI == 1) {
    b = z;
    In = wsb + OFF_ATT + (long)b * NSP * 512;
    W  = wsb + OFF_WF1;
  } else {
    b = z;
    In = wsb + OFF_H + (long)b * 802816;
    W  = wsb + OFF_WF2;
  }

  const int M0 = m0 + wm * 64;
  const u16* Abase = W + ((long)(M0 >> 4) * KB) * 512 + lane * 8;
  const u16* Bbase = In + ((long)((n0 >> 4) + wn * 2) * KB) * 512 + lane * 8;

  const f4 zero4 = {0.f, 0.f, 0.f, 0.f};
  f4 acc[4][2];
#pragma unroll
  for (int i = 0; i < 4; ++i)
#pragma unroll
    for (int j = 0; j < 2; ++j) acc[i][j] = zero4;

  const int kb0 = ks * (KB / SPLIT), kb1 = (ks + 1) * (KB / SPLIT);
#pragma unroll 8
  for (int kb = kb0; kb < kb1; ++kb) {
    bf8 aw[4], bx[2];
#pragma unroll
    for (int i = 0; i < 4; ++i)
      aw[i] = *(const bf8*)(Abase + ((long)i * KB + kb) * 512);
#pragma unroll
    for (int jn = 0; jn < 2; ++jn)
      bx[jn] = *(const bf8*)(Bbase + ((long)jn * KB + kb) * 512);
#pragma unroll
    for (int i = 0; i < 4; ++i)
#pragma unroll
      for (int jn = 0; jn < 2; ++jn)
        acc[i][jn] = __builtin_amdgcn_mfma_f32_16x16x32_bf16(aw[i], bx[jn], acc[i][jn], 0, 0, 0);
  }

  if constexpr (SPLIT == 2) {
    __shared__ f4 sc[2][2][8][64];
    if (ks) {
#pragma unroll
      for (int i = 0; i < 4; ++i)
#pragma unroll
        for (int j = 0; j < 2; ++j) sc[wm][wn][i * 2 + j][lane] = acc[i][j];
    }
    __syncthreads();
    if (ks) return;
#pragma unroll
    for (int i = 0; i < 4; ++i)
#pragma unroll
      for (int j = 0; j < 2; ++j) acc[i][j] += sc[wm][wn][i * 2 + j][lane];
  }

  const int seg = M0 >> 8;  // uniform per wave
#pragma unroll
  for (int i = 0; i < 4; ++i) {
    const int orow = M0 + i * 16 + 4 * g;  // + reg q
#pragma unroll
    for (int jn = 0; jn < 2; ++jn) {
      const int n = n0 + wn * 32 + jn * 16 + r;
      f4 a = acc[i][jn];
      if constexpr (EPI == 0) {
        const int ol = orow & 255;
        const float* bs = bcat + mod * 768 + seg * 256 + ol;
        const float qs = (seg == 0) ? SCQ : 1.0f;
        float a0 = (a.x + bs[0]) * qs, a1 = (a.y + bs[1]) * qs;
        float a2 = (a.z + bs[2]) * qs, a3 = (a.w + bs[3]) * qs;
        if (seg == 0) {
          const int hh = ol >> 5, hd0 = ol & 31;
          us4 pk; pk.x = f2bf(a0); pk.y = f2bf(a1); pk.z = f2bf(a2); pk.w = f2bf(a3);
          *(us4*)(wsb + OFF_QB + mod * SZ1
                  + (((long)(b * 8 + hh) * 196 + (n >> 4)) << 9)
                  + ((hd0 >> 3) * 16 + (n & 15)) * 8 + (hd0 & 7)) = pk;
        } else if (seg == 1) {
          const int hh = ol >> 5, hd0 = ol & 31;
          const int t = n >> 5, rr = n & 31;
          const int half = (rr >> 2) & 1, rK = ((rr >> 3) << 2) | (rr & 3);
          us4 pk; pk.x = f2bf(a0); pk.y = f2bf(a1); pk.z = f2bf(a2); pk.w = f2bf(a3);
          *(us4*)(wsb + OFF_KB + mod * SZ1
                  + ((((long)(b * 8 + hh) * 98 + t) * 2 + half) << 9)
                  + ((hd0 >> 3) * 16 + rK) * 8 + (hd0 & 7)) = pk;
        } else {
          const int hh = ol >> 5, rem = ol & 31, halfc = rem >> 4, rv = rem & 15;
          const int t = n >> 5, gp = (n >> 3) & 3, jj = n & 7;
          u16* dst = wsb + OFF_VB + mod * SZ1
                   + ((((long)(b * 8 + hh) * 98 + t) * 2 + halfc) << 9)
                   + (gp * 16 + rv) * 8 + jj;
          dst[0] = f2bf(a0); dst[8] = f2bf(a1); dst[16] = f2bf(a2); dst[24] = f2bf(a3);
        }
      } else if constexpr (EPI == 1) {
        us4 pk;
#pragma unroll
        for (int q = 0; q < 4; ++q) {
          const int o = orow + q;
          float v = (a[q] + bf1[o]) * (gamma[o] * 0.9999950000374994f) + beta[o];
          pk[q] = f2bf(fmaxf(v, 0.f));
        }
        const int ch0 = orow;
        *(us4*)(wsb + OFF_H + ((((long)b * 196 + (n >> 4)) * 8 + (ch0 >> 5)) << 9)
                + (((ch0 >> 3) & 3) * 16 + (n & 15)) * 8 + (ch0 & 7)) = pk;
      } else {
#pragma unroll
        for (int q = 0; q < 4; ++q) {
          const int o = orow + q;
          outf[(long)(b * 256 + o) * NSP + n] = a[q] + bf2[o];
        }
      }
    }
  }
}

// ---------------- flash attention (no-max softmax; fragment-major Q/K/V) ----------------
// 8 waves/block = (qhalf x 4-way kv-split); 32 q-rows/wave; additive LDS combine.
// z==2 slice: attention-map partial reduction (112 active blocks).
DEV bf8 pack_p(f4 s0, f4 s1) {
  union { unsigned u[4]; bf8 v; } p;
  float a0 = __builtin_amdgcn_exp2f(s0.x), a1 = __builtin_amdgcn_exp2f(s0.y);
  float a2 = __builtin_amdgcn_exp2f(s0.z), a3 = __builtin_amdgcn_exp2f(s0.w);
  float a4 = __builtin_amdgcn_exp2f(s1.x), a5 = __builtin_amdgcn_exp2f(s1.y);
  float a6 = __builtin_amdgcn_exp2f(s1.z), a7 = __builtin_amdgcn_exp2f(s1.w);
  asm("v_cvt_pk_bf16_f32 %0, %1, %2" : "=v"(p.u[0]) : "v"(a0), "v"(a1));
  asm("v_cvt_pk_bf16_f32 %0, %1, %2" : "=v"(p.u[1]) : "v"(a2), "v"(a3));
  asm("v_cvt_pk_bf16_f32 %0, %1, %2" : "=v"(p.u[2]) : "v"(a4), "v"(a5));
  asm("v_cvt_pk_bf16_f32 %0, %1, %2" : "=v"(p.u[3]) : "v"(a6), "v"(a7));
  return p.v;
}

__global__ __launch_bounds__(512) void k_attn(u16* __restrict__ wsb,
                                              float* __restrict__ qsums,
                                              float* __restrict__ ksums) {
  const int tid = threadIdx.x;
  if (blockIdx.z == 2) {
    // ---- amap partial reduction: per-(bh, d) column sums of Q_rgb, K_depth ----
    if (blockIdx.x >= 7 || tid >= 256) return;
    const int split = blockIdx.x;
    const int bh = blockIdx.y;
    const int d = tid & 31, ns = tid >> 5;
    const u16* qb = wsb + OFF_QB + ((long)bh * 196) * 512 + ((d >> 3) * 16) * 8 + (d & 7);
    const u16* kb = wsb + OFF_KB + SZ1 + ((long)bh * 196) * 512 + ((d >> 3) * 16) * 8 + (d & 7);
    float qs = 0.f, ks = 0.f;
    for (int u = split * 28 + ns; u < split * 28 + 28; u += 8) {
      const long ub = (long)u << 9;
#pragma unroll
      for (int rr = 0; rr < 16; ++rr) {
        qs += bf2f(qb[ub + rr * 8]);
        ks += bf2f(kb[ub + rr * 8]);
      }
    }
    __shared__ float sq[256], sk[256];
    sq[tid] = qs; sk[tid] = ks;
    __syncthreads();
    if (tid < 32) {
#pragma unroll
      for (int j = 1; j < 8; ++j) { qs += sq[tid + 32 * j]; ks += sk[tid + 32 * j]; }
      atomicAdd(qsums + bh * 32 + tid, qs);
      atomicAdd(ksums + bh * 32 + tid, ks);
    }
    return;
  }

  const int m = blockIdx.z;
  const int bh = blockIdx.y;
  const int b = bh >> 3, h = bh & 7;
  const int lane = tid & 63, wid = tid >> 6;
  const int qh = wid & 1, kvh = wid >> 1;    // qh 0..1, kvh 0..3
  const int g = lane >> 4, r = lane & 15;
  const int q0 = blockIdx.x * 64 + qh * 32;

  const u16* QF = wsb + OFF_QB + (long)m * SZ1 + ((long)bh * 196) * 512;
  const u16* KF = wsb + OFF_KB + (long)(1 - m) * SZ1 + ((long)bh * 196) * 512;
  const u16* VF = wsb + OFF_VB + (long)(1 - m) * SZ1 + ((long)bh * 196) * 512;

  const bf8 qfA = *(const bf8*)(QF + ((long)(q0 >> 4) << 9) + lane * 8);
  const bf8 qfB = *(const bf8*)(QF + ((long)((q0 >> 4) + 1) << 9) + lane * 8);
  // kv 64-row tiles: 49 total, split 13/12/12/12 across kvh
  const int tb = kvh ? (13 + 12 * (kvh - 1)) : 0;
  const int te = tb + (kvh ? 12 : 13);
  const u16* kp = KF + ((long)tb << 11) + lane * 8;
  const u16* vp = VF + ((long)tb << 11) + lane * 8;

  bf8 ones;
#pragma unroll
  for (int j = 0; j < 8; ++j) ones[j] = (short)0x3F80;  // bf16 1.0

  const f4 zero4 = {0.f, 0.f, 0.f, 0.f};
  f4 oA0 = zero4, oA1 = zero4, oB0 = zero4, oB1 = zero4;
  f4 lA = zero4, lB = zero4;

  for (int t = tb; t < te; ++t) {
    const bf8 kf0 = *(const bf8*)(kp);
    const bf8 kf1 = *(const bf8*)(kp + 512);
    const bf8 kf2 = *(const bf8*)(kp + 1024);
    const bf8 kf3 = *(const bf8*)(kp + 1536);
    kp += 2048;
    const bf8 v0a = *(const bf8*)(vp);
    const bf8 v1a = *(const bf8*)(vp + 512);
    const bf8 v0b = *(const bf8*)(vp + 1024);
    const bf8 v1b = *(const bf8*)(vp + 1536);
    vp += 2048;

    // group A (q = q0 + r)
    {
      f4 s0 = __builtin_amdgcn_mfma_f32_16x16x32_bf16(kf0, qfA, zero4, 0, 0, 0);
      f4 s1 = __builtin_amdgcn_mfma_f32_16x16x32_bf16(kf1, qfA, zero4, 0, 0, 0);
      f4 s2 = __builtin_amdgcn_mfma_f32_16x16x32_bf16(kf2, qfA, zero4, 0, 0, 0);
      f4 s3 = __builtin_amdgcn_mfma_f32_16x16x32_bf16(kf3, qfA, zero4, 0, 0, 0);
      bf8 p0 = pack_p(s0, s1);   // kv .. kv+31
      bf8 p1 = pack_p(s2, s3);   // kv+32 .. kv+63
      lA  = __builtin_amdgcn_mfma_f32_16x16x32_bf16(ones, p0, lA, 0, 0, 0);
      lA  = __builtin_amdgcn_mfma_f32_16x16x32_bf16(ones, p1, lA, 0, 0, 0);
      oA0 = __builtin_amdgcn_mfma_f32_16x16x32_bf16(v0a, p0, oA0, 0, 0, 0);
      oA0 = __builtin_amdgcn_mfma_f32_16x16x32_bf16(v0b, p1, oA0, 0, 0, 0);
      oA1 = __builtin_amdgcn_mfma_f32_16x16x32_bf16(v1a, p0, oA1, 0, 0, 0);
      oA1 = __builtin_amdgcn_mfma_f32_16x16x32_bf16(v1b, p1, oA1, 0, 0, 0);
    }
    // group B (q = q0 + 16 + r)
    {
      f4 s0 = __builtin_amdgcn_mfma_f32_16x16x32_bf16(kf0, qfB, zero4, 0, 0, 0);
      f4 s1 = __builtin_amdgcn_mfma_f32_16x16x32_bf16(kf1, qfB, zero4, 0, 0, 0);
      f4 s2 = __builtin_amdgcn_mfma_f32_16x16x32_bf16(kf2, qfB, zero4, 0, 0, 0);
      f4 s3 = __builtin_amdgcn_mfma_f32_16x16x32_bf16(kf3, qfB, zero4, 0, 0, 0);
      bf8 p0 = pack_p(s0, s1);
      bf8 p1 = pack_p(s2, s3);
      lB  = __builtin_amdgcn_mfma_f32_16x16x32_bf16(ones, p0, lB, 0, 0, 0);
      lB  = __builtin_amdgcn_mfma_f32_16x16x32_bf16(ones, p1, lB, 0, 0, 0);
      oB0 = __builtin_amdgcn_mfma_f32_16x16x32_bf16(v0a, p0, oB0, 0, 0, 0);
      oB0 = __builtin_amdgcn_mfma_f32_16x16x32_bf16(v0b, p1, oB0, 0, 0, 0);
      oB1 = __builtin_amdgcn_mfma_f32_16x16x32_bf16(v1a, p0, oB1, 0, 0, 0);
      oB1 = __builtin_amdgcn_mfma_f32_16x16x32_bf16(v1b, p1, oB1, 0, 0, 0);
    }
  }

  // combine 4 kv-partials per q-half (additive: no-max softmax) via LDS
  __shared__ f4 so[2][3][4][64];
  __shared__ float sl[2][3][2][64];
  if (kvh) {
    so[qh][kvh - 1][0][lane] = oA0; so[qh][kvh - 1][1][lane] = oA1;
    so[qh][kvh - 1][2][lane] = oB0; so[qh][kvh - 1][3][lane] = oB1;
    sl[qh][kvh - 1][0][lane] = lA.x; sl[qh][kvh - 1][1][lane] = lB.x;
  }
  __syncthreads();
  if (!kvh) {
#pragma unroll
    for (int w = 0; w < 3; ++w) {
      oA0 += so[qh][w][0][lane]; oA1 += so[qh][w][1][lane];
      oB0 += so[qh][w][2][lane]; oB1 += so[qh][w][3][lane];
      lA.x += sl[qh][w][0][lane]; lB.x += sl[qh][w][1][lane];
    }
    const float invA = 1.0f / lA.x;
    const float invB = 1.0f / lB.x;
    oA0 *= invA; oA1 *= invA; oB0 *= invB; oB1 *= invB;

    // ATT fragment layout: [b][196 u][16 kblk][512]; n = q0+r (A) / q0+16+r (B)
    u16* ab = wsb + OFF_ATT + ((((long)b * 196 + (q0 >> 4)) * 16) + m * 8 + h) * 512;
    const int ld0 = ((g >> 1) * 16 + r) * 8 + 4 * (g & 1);
    us4 w0, w1, w2, w3;
#pragma unroll
    for (int q = 0; q < 4; ++q) {
      w0[q] = f2bf(oA0[q]); w1[q] = f2bf(oA1[q]);
      w2[q] = f2bf(oB0[q]); w3[q] = f2bf(oB1[q]);
    }
    *(us4*)(ab + ld0) = w0;
    *(us4*)(ab + ld0 + 256) = w1;
    *(us4*)(ab + 8192 + ld0) = w2;
    *(us4*)(ab + 8192 + ld0 + 256) = w3;
  }
}

// ---------------- launch ----------------
extern "C" void kernel_launch(void* const* d_in, const int* in_sizes, int n_in,
                              void* d_out, int out_size, void* d_ws, size_t ws_size,
                              hipStream_t stream) {
  const float* rgb   = (const float*)d_in[0];
  const float* dep   = (const float*)d_in[1];
  const float* Wq_rd = (const float*)d_in[2];
  const float* bq_rd = (const float*)d_in[3];
  const float* Wk_d  = (const float*)d_in[4];
  const float* bk_d  = (const float*)d_in[5];
  const float* Wv_d  = (const float*)d_in[6];
  const float* bv_d  = (const float*)d_in[7];
  const float* Wq_dr = (const float*)d_in[8];
  const float* bq_dr = (const float*)d_in[9];
  const float* Wk_r  = (const float*)d_in[10];
  const float* bk_r  = (const float*)d_in[11];
  const float* Wv_r  = (const float*)d_in[12];
  const float* bv_r  = (const float*)d_in[13];
  const float* Wf1   = (const float*)d_in[14];
  const float* bf1   = (const float*)d_in[15];
  const float* gamma = (const float*)d_in[16];
  const float* beta  = (const float*)d_in[17];
  const float* Wf2   = (const float*)d_in[18];
  const float* bf2   = (const float*)d_in[19];
  float* out = (float*)d_out;

  u16* wsb = (u16*)d_ws;
  float* wsf = (float*)((char*)d_ws + (size_t)END_BF16 * 2);
  float* qsums = wsf + 4;        // 512
  float* ksums = wsf + 4 + 512;  // 512
  float* bcat  = wsf + 1028;     // 1536
  const size_t needed = (size_t)END_BF16 * 2 + (4 + 1024 + 1536) * sizeof(float);
  if (ws_size < needed) return;

  k_cvtprep<<<2511, 256, 0, stream>>>(rgb, dep,
                                      Wq_rd, Wk_r, Wv_r, Wq_dr, Wk_d, Wv_d, Wf1, Wf2,
                                      bq_rd, bk_r, bv_r, bq_dr, bk_d, bv_d, wsb, wsf);
  k_gemm<256, 0, 1><<<dim3(49, 6, 4), 256, 0, stream>>>(wsb, bcat, nullptr, nullptr, nullptr, nullptr, nullptr, nullptr, nullptr);
  k_attn<<<dim3(49, 16, 3), 512, 0, stream>>>(wsb, qsums, ksums);
  k_gemm<512, 1, 2><<<dim3(49, 2, 3), 512, 0, stream>>>(wsb, nullptr, bf1, gamma, beta, nullptr, qsums, ksums, out);
  k_gemm<256, 2, 2><<<dim3(49, 2, 2), 512, 0, stream>>>(wsb, nullptr, nullptr, nullptr, nullptr, bf2, nullptr, nullptr, out);
}